// Round 8
// baseline (56.888 us; speedup 1.0000x reference)
//
#include <hip/hip_runtime.h>
#include <hip/hip_bf16.h>

typedef __attribute__((ext_vector_type(8))) short short8;
typedef __attribute__((ext_vector_type(4))) float f32x4;

#define DEG 5
#define FDIM 128
#define MT 32          // nodes per tile (persistent kernel)
#define NTHR 256
#define LROW 136       // 128 + 8 shorts pad (VALU-staged LDS, pad OK)
#define NBG 625        // persistent grid: 625 * 5 tiles = 3125 = 100000/32

// Exact collapse of the Shapley subset enumeration (slots symmetric, c1
// depends only on |S|):  s_i = (1 + 147/360) x_i + (-29/600) sum_j x_nbr[j]
#define CSELF 1.4083333333333334f
#define ALPHA (-0.04833333333333333f)

__device__ __forceinline__ short f2bf(float f) {
    unsigned u = __builtin_bit_cast(unsigned, f);
    unsigned r = (u + 0x7fffu + ((u >> 16) & 1u)) >> 16;
    return (short)(r & 0xffffu);
}
__device__ __forceinline__ float bf2f(short s) {
    return __builtin_bit_cast(float, (unsigned)((unsigned short)s) << 16);
}

// ---- prep: W (fp32 [128][128]) -> bf16 fragments in MFMA fragment-linear order ----
__global__ __launch_bounds__(256) void prep_w_kernel(
    const float* __restrict__ W, short* __restrict__ wswz)
{
    int t = blockIdx.x * 256 + threadIdx.x;   // 0..2047
    int frag = t >> 6;
    int lane = t & 63;
    int tt = frag >> 2;
    int kk = frag & 3;
    int lr = lane & 15;
    int lg = lane >> 4;
    const float4* wp = reinterpret_cast<const float4*>(W + (tt * 16 + lr) * FDIM + kk * 32 + lg * 8);
    float4 w0 = wp[0], w1 = wp[1];
    short8 v;
    v[0] = f2bf(w0.x); v[1] = f2bf(w0.y); v[2] = f2bf(w0.z); v[3] = f2bf(w0.w);
    v[4] = f2bf(w1.x); v[5] = f2bf(w1.y); v[6] = f2bf(w1.z); v[7] = f2bf(w1.w);
    *reinterpret_cast<short8*>(wswz + (size_t)t * 8) = v;
}

// ---- k1: xb = bf16(x), streaming convert (8 elems/thread) ----
__global__ __launch_bounds__(256) void conv_xb_kernel(
    const float* __restrict__ x, short* __restrict__ xb, long total8)
{
    long t = (long)blockIdx.x * 256 + threadIdx.x;
    if (t < total8) {
        const f32x4* xp = reinterpret_cast<const f32x4*>(x + t * 8);
        f32x4 a = xp[0], b = xp[1];
        short8 v;
        v[0] = f2bf(a[0]); v[1] = f2bf(a[1]); v[2] = f2bf(a[2]); v[3] = f2bf(a[3]);
        v[4] = f2bf(b[0]); v[5] = f2bf(b[1]); v[6] = f2bf(b[2]); v[7] = f2bf(b[3]);
        *reinterpret_cast<short8*>(xb + t * 8) = v;
    }
}

// ---- persistent fused kernel: register double-buffered tile pipeline ----
// Per tile (32 nodes): load idx + self + 5 nbr rows (bf16, reg-staged) for
// tile t+1 BEFORE computing tile t (combine -> LDS -> MFMA -> store).
struct SetRegs {
    short8 self[2];
    short8 nb[2][DEG];
    int tbase;
    int valid;
};

__device__ __forceinline__ void load_tile(
    SetRegs& S, int tt, int NT,
    const short* __restrict__ xb, const int* __restrict__ col,
    int n, int tid)
{
    S.valid = (tt < NT);
    int tb = (S.valid ? tt : 0) * MT;
    S.tbase = tb;
    const int c = tid & 15;
    const int srow = tid >> 4;                 // 0..15
    #pragma unroll
    for (int u = 0; u < 2; ++u) {
        int node = tb + u * 16 + srow;
        int nc = node < n ? node : 0;
        S.self[u] = *reinterpret_cast<const short8*>(xb + (size_t)nc * FDIM + c * 8);
        #pragma unroll
        for (int j = 0; j < DEG; ++j) {
            int nbr = col[nc * DEG + j];       // same addr across 16 c-lanes -> broadcast
            S.nb[u][j] = *reinterpret_cast<const short8*>(xb + (size_t)nbr * FDIM + c * 8);
        }
    }
}

__device__ __forceinline__ void comp_tile(
    const SetRegs& S, short* sS,
    const short* __restrict__ wswz, float* __restrict__ out,
    int n, int tid)
{
    const int c = tid & 15;
    const int srow = tid >> 4;

    // combine -> bf16 LDS
    #pragma unroll
    for (int u = 0; u < 2; ++u) {
        int row = u * 16 + srow;
        short8 v;
        #pragma unroll
        for (int k = 0; k < 8; ++k) {
            float s = bf2f(S.nb[u][0][k]) + bf2f(S.nb[u][1][k]) + bf2f(S.nb[u][2][k])
                    + bf2f(S.nb[u][3][k]) + bf2f(S.nb[u][4][k]);
            float vf = CSELF * bf2f(S.self[u][k]) + ALPHA * s;
            v[k] = f2bf(vf);
        }
        *reinterpret_cast<short8*>(&sS[row * LROW + c * 8]) = v;
    }
    __syncthreads();

    // MFMA: wave w -> row-tile (w&1), col-tiles (w>>1)*4 .. +4
    const int wave = tid >> 6;
    const int lane = tid & 63;
    const int lr = lane & 15;
    const int lg = lane >> 4;
    const int rt = wave & 1;
    const int cg = wave >> 1;

    short8 af[4];
    const short* arow = &sS[(rt * 16 + lr) * LROW];
    #pragma unroll
    for (int kk = 0; kk < 4; ++kk)
        af[kk] = *reinterpret_cast<const short8*>(arow + kk * 32 + lg * 8);
    __syncthreads();   // sS free for next tile's staging

    f32x4 acc[4];
    #pragma unroll
    for (int q = 0; q < 4; ++q) acc[q] = (f32x4){0.f, 0.f, 0.f, 0.f};

    #pragma unroll
    for (int q = 0; q < 4; ++q) {
        int tcol = cg * 4 + q;
        #pragma unroll
        for (int kk = 0; kk < 4; ++kk) {
            short8 bf = *reinterpret_cast<const short8*>(
                wswz + (((size_t)(tcol * 4 + kk) * 64 + lane) * 8));
            acc[q] = __builtin_amdgcn_mfma_f32_16x16x32_bf16(af[kk], bf, acc[q], 0, 0, 0);
        }
    }

    // epilogue: relu + store (D[(lg*4+i)][tcol*16+lr])
    #pragma unroll
    for (int q = 0; q < 4; ++q) {
        #pragma unroll
        for (int i = 0; i < 4; ++i) {
            int nrow = S.tbase + rt * 16 + lg * 4 + i;
            if (nrow < n) {
                float v = acc[q][i];
                out[(size_t)nrow * FDIM + (cg * 4 + q) * 16 + lr] = v > 0.f ? v : 0.f;
            }
        }
    }
}

__global__ __launch_bounds__(NTHR) void shapley_persistent_kernel(
    const short* __restrict__ xb,
    const int* __restrict__ col,
    const short* __restrict__ wswz,
    float* __restrict__ out,
    int n, int NT)
{
    __shared__ short sS[MT * LROW];
    const int tid = threadIdx.x;
    const int b = blockIdx.x;
    const int G = gridDim.x;

    SetRegs A, B;
    load_tile(A, b, NT, xb, col, n, tid);
    int k = 0;
    while (true) {
        load_tile(B, b + (k + 1) * G, NT, xb, col, n, tid);   // prefetch next
        if (A.valid) comp_tile(A, sS, wswz, out, n, tid);     // block-uniform
        ++k;
        if (b + (size_t)k * G >= (size_t)NT) break;
        load_tile(A, b + (k + 1) * G, NT, xb, col, n, tid);
        if (B.valid) comp_tile(B, sS, wswz, out, n, tid);
        ++k;
        if (b + (size_t)k * G >= (size_t)NT) break;
    }
}

// ---- fallback (fp32-gather fused, round-2 style) if d_ws too small ----
__global__ __launch_bounds__(NTHR) void shapley_fb_kernel(
    const float* __restrict__ x,
    const int* __restrict__ col,
    const short* __restrict__ wswz,
    float* __restrict__ out,
    int n)
{
    __shared__ short sS[64 * LROW];
    __shared__ int sIdx[64 * DEG];

    const int tid = threadIdx.x;
    const int base = blockIdx.x * 64;

    for (int i = tid; i < 64 * DEG; i += NTHR) {
        int e = base * DEG + i;
        sIdx[i] = (e < n * DEG) ? col[e] : 0;
    }
    __syncthreads();

    for (int t = tid; t < 64 * 16; t += NTHR) {
        int m = t >> 4;
        int c = t & 15;
        int node = base + m;
        float a0, a1, a2, a3, a4, a5, a6, a7;
        if (node < n) {
            const float4* xp = reinterpret_cast<const float4*>(x + (size_t)node * FDIM + c * 8);
            float4 s0 = xp[0], s1 = xp[1];
            a0 = CSELF * s0.x; a1 = CSELF * s0.y; a2 = CSELF * s0.z; a3 = CSELF * s0.w;
            a4 = CSELF * s1.x; a5 = CSELF * s1.y; a6 = CSELF * s1.z; a7 = CSELF * s1.w;
            #pragma unroll
            for (int j = 0; j < DEG; ++j) {
                int nb = sIdx[m * DEG + j];
                const float4* np = reinterpret_cast<const float4*>(x + (size_t)nb * FDIM + c * 8);
                float4 b0 = np[0], b1 = np[1];
                a0 += ALPHA * b0.x; a1 += ALPHA * b0.y; a2 += ALPHA * b0.z; a3 += ALPHA * b0.w;
                a4 += ALPHA * b1.x; a5 += ALPHA * b1.y; a6 += ALPHA * b1.z; a7 += ALPHA * b1.w;
            }
        } else {
            a0 = a1 = a2 = a3 = a4 = a5 = a6 = a7 = 0.f;
        }
        short8 v;
        v[0] = f2bf(a0); v[1] = f2bf(a1); v[2] = f2bf(a2); v[3] = f2bf(a3);
        v[4] = f2bf(a4); v[5] = f2bf(a5); v[6] = f2bf(a6); v[7] = f2bf(a7);
        *reinterpret_cast<short8*>(&sS[m * LROW + c * 8]) = v;
    }
    __syncthreads();

    const int wave = tid >> 6;
    const int lane = tid & 63;
    const int lr = lane & 15;
    const int lg = lane >> 4;

    short8 afrag[4];
    const short* arow = &sS[(wave * 16 + lr) * LROW];
    #pragma unroll
    for (int kk = 0; kk < 4; ++kk)
        afrag[kk] = *reinterpret_cast<const short8*>(arow + kk * 32 + lg * 8);

    f32x4 acc[8];
    #pragma unroll
    for (int t = 0; t < 8; ++t) acc[t] = (f32x4){0.f, 0.f, 0.f, 0.f};

    #pragma unroll
    for (int t = 0; t < 8; ++t) {
        #pragma unroll
        for (int kk = 0; kk < 4; ++kk) {
            short8 bfrag = *reinterpret_cast<const short8*>(
                wswz + (((size_t)(t * 4 + kk) * 64 + lane) * 8));
            acc[t] = __builtin_amdgcn_mfma_f32_16x16x32_bf16(afrag[kk], bfrag, acc[t], 0, 0, 0);
        }
    }

    #pragma unroll
    for (int t = 0; t < 8; ++t) {
        #pragma unroll
        for (int i = 0; i < 4; ++i) {
            int nrow = base + wave * 16 + lg * 4 + i;
            if (nrow < n) {
                float v = acc[t][i];
                out[(size_t)nrow * FDIM + t * 16 + lr] = v > 0.f ? v : 0.f;
            }
        }
    }
}

extern "C" void kernel_launch(void* const* d_in, const int* in_sizes, int n_in,
                              void* d_out, int out_size, void* d_ws, size_t ws_size,
                              hipStream_t stream) {
    const float* x  = (const float*)d_in[0];
    const int* ei   = (const int*)d_in[1];
    const float* W  = (const float*)d_in[2];
    float* out      = (float*)d_out;

    int n = in_sizes[0] / FDIM;                   // 100000 nodes
    const int* col = ei + (size_t)n * DEG;        // second row of edge_index

    short* wswz = (short*)d_ws;                   // 32 KB fragment buffer
    size_t xb_off = 32768;
    size_t need   = xb_off + (size_t)n * FDIM * sizeof(short);  // + 25.6 MB bf16 x

    hipLaunchKernelGGL(prep_w_kernel, dim3(8), dim3(256), 0, stream, W, wswz);

    if (ws_size >= need) {
        short* xb = (short*)((char*)d_ws + xb_off);
        long total8 = (long)n * FDIM / 8;
        int cblocks = (int)((total8 + 255) / 256);
        hipLaunchKernelGGL(conv_xb_kernel, dim3(cblocks), dim3(256), 0, stream,
                           x, xb, total8);
        int NT = (n + MT - 1) / MT;               // 3125 tiles
        int g = NT < NBG ? NT : NBG;              // 625 persistent blocks
        hipLaunchKernelGGL(shapley_persistent_kernel, dim3(g), dim3(NTHR), 0, stream,
                           xb, col, wswz, out, n, NT);
    } else {
        int blocks = (n + 63) / 64;
        hipLaunchKernelGGL(shapley_fb_kernel, dim3(blocks), dim3(NTHR), 0, stream,
                           x, col, wswz, out, n);
    }
}